// Round 1
// 102.626 us; speedup vs baseline: 1.0040x; 1.0040x over previous
//
#include <hip/hip_runtime.h>
#include <math.h>

// ScorePredictor: out[e] = sigmoid(x[src[e]] . w_s + x[dst[e]] . w_d + b)
// Factored: p_s[n] = x[n].w_s ; p_d[n] = x[n].w_d  (one coalesced pass over x)
// then     out[e] = sigmoid(p_s[src[e]] + p_d[dst[e]] + b)  (gathers hit L2)

#define DIM 128

// proj v2: persistent grid-stride kernel, 8 lanes per node.
// Each 8-lane group owns one node per iteration. Lane j loads 4 float4s
// (chunks k=0..3 at float4-index k*8+j), so per load-instruction a wave
// covers 8 consecutive nodes' 128B segments (fully coalescable lines).
// Reduction is a width-8 butterfly: 3 levels x 2 values = 6 shuffle
// instructions per wave per 8 nodes (vs 80 in the old 32-lane scheme).
// 4 independent global loads in flight per lane hides HBM latency.
__global__ __launch_bounds__(256) void proj_kernel(
    const float* __restrict__ x,
    const float* __restrict__ W,   // 256 floats: [w_s | w_d]
    float* __restrict__ ps,
    float* __restrict__ pd,
    int n_nodes)
{
    const int j = threadIdx.x & 7;                       // lane within group
    const int G = (blockIdx.x * blockDim.x + threadIdx.x) >> 3;  // global group id
    const int stride = (gridDim.x * blockDim.x) >> 3;    // total groups

    const float4* __restrict__ x4 = (const float4*)x;
    const float4* __restrict__ w4 = (const float4*)W;

    // per-lane weight slices (8 float4s, loaded once, L1/L2-hot)
    const float4 ws0 = w4[j],      ws1 = w4[8 + j],
                 ws2 = w4[16 + j], ws3 = w4[24 + j];
    const float4 wd0 = w4[32 + j],      wd1 = w4[40 + j],
                 wd2 = w4[48 + j],      wd3 = w4[56 + j];

    for (int node = G; node < n_nodes; node += stride) {
        const size_t base = (size_t)node * (DIM / 4);
        // 4 independent 16B loads in flight
        float4 v0 = x4[base + 0 * 8 + j];
        float4 v1 = x4[base + 1 * 8 + j];
        float4 v2 = x4[base + 2 * 8 + j];
        float4 v3 = x4[base + 3 * 8 + j];

        float s = v0.x * ws0.x + v0.y * ws0.y + v0.z * ws0.z + v0.w * ws0.w
                + v1.x * ws1.x + v1.y * ws1.y + v1.z * ws1.z + v1.w * ws1.w
                + v2.x * ws2.x + v2.y * ws2.y + v2.z * ws2.z + v2.w * ws2.w
                + v3.x * ws3.x + v3.y * ws3.y + v3.z * ws3.z + v3.w * ws3.w;
        float d = v0.x * wd0.x + v0.y * wd0.y + v0.z * wd0.z + v0.w * wd0.w
                + v1.x * wd1.x + v1.y * wd1.y + v1.z * wd1.z + v1.w * wd1.w
                + v2.x * wd2.x + v2.y * wd2.y + v2.z * wd2.z + v2.w * wd2.w
                + v3.x * wd3.x + v3.y * wd3.y + v3.z * wd3.z + v3.w * wd3.w;

        // width-8 butterfly: 3 levels, both values
        #pragma unroll
        for (int off = 4; off > 0; off >>= 1) {
            s += __shfl_down(s, off, 8);
            d += __shfl_down(d, off, 8);
        }
        if (j == 0) {
            ps[node] = s;    // 8 active lanes/wave, consecutive nodes -> coalesced 32B
            pd[node] = d;
        }
    }
}

// edge v2: 4 edges per thread. int4 loads of src/dst, float4 store of out,
// 8 independent L2 gathers in flight per thread.
__global__ __launch_bounds__(256) void edge_kernel(
    const int* __restrict__ src,
    const int* __restrict__ dst,
    const float* __restrict__ ps,
    const float* __restrict__ pd,
    const float* __restrict__ b,
    float* __restrict__ out,
    int n_edges)
{
    const int nQuad = n_edges >> 2;
    const int q = blockIdx.x * blockDim.x + threadIdx.x;
    const float bb = b[0];

    if (q < nQuad) {
        const int4 s4 = ((const int4*)src)[q];
        const int4 d4 = ((const int4*)dst)[q];
        const float z0 = ps[s4.x] + pd[d4.x] + bb;
        const float z1 = ps[s4.y] + pd[d4.y] + bb;
        const float z2 = ps[s4.z] + pd[d4.z] + bb;
        const float z3 = ps[s4.w] + pd[d4.w] + bb;
        float4 o;
        o.x = 1.0f / (1.0f + __expf(-z0));
        o.y = 1.0f / (1.0f + __expf(-z1));
        o.z = 1.0f / (1.0f + __expf(-z2));
        o.w = 1.0f / (1.0f + __expf(-z3));
        ((float4*)out)[q] = o;
    } else if (q == nQuad) {
        // scalar tail (n_edges % 4 edges), single thread
        for (int e = nQuad * 4; e < n_edges; ++e) {
            const float z = ps[src[e]] + pd[dst[e]] + bb;
            out[e] = 1.0f / (1.0f + __expf(-z));
        }
    }
}

extern "C" void kernel_launch(void* const* d_in, const int* in_sizes, int n_in,
                              void* d_out, int out_size, void* d_ws, size_t ws_size,
                              hipStream_t stream) {
    const float* x   = (const float*)d_in[0];
    const int*   src = (const int*)d_in[1];
    const int*   dst = (const int*)d_in[2];
    const float* W   = (const float*)d_in[3];
    const float* b   = (const float*)d_in[4];
    float* out = (float*)d_out;

    const int n_nodes = in_sizes[0] / DIM;
    const int n_edges = in_sizes[1];

    float* ps = (float*)d_ws;            // n_nodes floats
    float* pd = ps + n_nodes;            // n_nodes floats  (800 KB total)

    // proj: persistent grid-stride, 32 nodes per block per round.
    int proj_blocks = (n_nodes + 31) / 32;
    if (proj_blocks > 1024) proj_blocks = 1024;   // 4 blocks/CU, 16 waves/CU
    proj_kernel<<<proj_blocks, 256, 0, stream>>>(x, W, ps, pd, n_nodes);

    // edge: one quad (4 edges) per thread + 1 tail thread.
    const int nQuad = n_edges >> 2;
    const int edge_blocks = (nQuad + 1 + 255) / 256;
    edge_kernel<<<edge_blocks, 256, 0, stream>>>(src, dst, ps, pd, b, out, n_edges);
}